// Round 20
// baseline (214.493 us; speedup 1.0000x reference)
//
#include <hip/hip_runtime.h>
#include <hip/hip_fp16.h>
#include <cstdint>

#define NEG_SLOPE 0.2f
#define MAXDEG 64

typedef __attribute__((ext_vector_type(8))) short bf16x8;
typedef __attribute__((ext_vector_type(4))) float f32x4;
typedef _Float16 h2_t __attribute__((ext_vector_type(2)));

__device__ inline short bf16_rne(float x) {
    uint32_t u = __float_as_uint(x);
    return (short)((u + 0x7FFF + ((u >> 16) & 1)) >> 16);
}
__device__ inline float bf16_to_f32(short s) {
    uint32_t u = ((uint32_t)(uint16_t)s) << 16;
    return __uint_as_float(u);
}
__device__ inline float fdot2(__half2 a, __half2 b, float c) {
    return __builtin_amdgcn_fdot2(*(h2_t*)&a, *(h2_t*)&b, c, false);
}
// ROCm 7.2 hip_fp16.h lacks __hmax2 -> packed max via v_pk_max_f16
__device__ inline __half2 hmax2(__half2 a, __half2 b) {
    uint32_t au = *(uint32_t*)&a, bu = *(uint32_t*)&b, du;
    asm("v_pk_max_f16 %0, %1, %2" : "=v"(du) : "v"(au), "v"(bu));
    return *(__half2*)&du;
}
// mixed-precision FMA: f32 = f32 * f16(lo/hi of u32) + f32 — fuses cvt+fma
__device__ inline float fma_mix_lo(float e, uint32_t xh, float c) {
    float d;
    asm("v_fma_mix_f32 %0, %1, %2, %3 op_sel_hi:[0,1,0]" : "=v"(d) : "v"(e), "v"(xh), "v"(c));
    return d;
}
__device__ inline float fma_mix_hi(float e, uint32_t xh, float c) {
    float d;
    asm("v_fma_mix_f32 %0, %1, %2, %3 op_sel:[0,1,0] op_sel_hi:[0,1,0]" : "=v"(d) : "v"(e), "v"(xh), "v"(c));
    return d;
}
// DPP all-reduce within 8-lane groups (VALU-speed, avoids LDS-pipe shfl latency).
template <int CTRL, int RMASK, int BMASK, bool BC>
__device__ inline float dpp_add(float v) {
    int t = __builtin_amdgcn_update_dpp(0, __float_as_int(v), CTRL, RMASK, BMASK, BC);
    return v + __int_as_float(t);
}
__device__ inline float red8(float p) {                        // sum over 8-lane head group
    p = dpp_add<0xB1, 0xF, 0xF, true>(p);   // quad_perm [1,0,3,2] : xor 1
    p = dpp_add<0x4E, 0xF, 0xF, true>(p);   // quad_perm [2,3,0,1] : xor 2
    int a = __builtin_amdgcn_update_dpp(0, __float_as_int(p), 0x114, 0xF, 0xA, false); // row_shr:4
    int b = __builtin_amdgcn_update_dpp(0, __float_as_int(p), 0x104, 0xF, 0x5, false); // row_shl:4
    return p + __int_as_float(a) + __int_as_float(b);
}

// ---------------- bucketed CSR build: 1 atomic per edge, 8 edges/thread ----------------
// bucket record = { src<<8 (byte offset of fp16 row), w (f32 bits) }

__global__ __launch_bounds__(256) void k_fillb(const int* __restrict__ ei, const float* __restrict__ ew,
                                               int* __restrict__ cursor, int2* __restrict__ bucket, int E) {
    int i0 = (blockIdx.x * 256 + threadIdx.x) * 8;
    if (i0 >= E) return;
    if (i0 + 7 < E) {
        int4 sa = *(const int4*)&ei[i0];
        int4 sb = *(const int4*)&ei[i0 + 4];
        int4 da = *(const int4*)&ei[E + i0];
        int4 db = *(const int4*)&ei[E + i0 + 4];
        float4 wa = *(const float4*)&ew[i0];
        float4 wb = *(const float4*)&ew[i0 + 4];
        int p0 = atomicAdd(&cursor[da.x], 1);
        int p1 = atomicAdd(&cursor[da.y], 1);
        int p2 = atomicAdd(&cursor[da.z], 1);
        int p3 = atomicAdd(&cursor[da.w], 1);
        int p4 = atomicAdd(&cursor[db.x], 1);
        int p5 = atomicAdd(&cursor[db.y], 1);
        int p6 = atomicAdd(&cursor[db.z], 1);
        int p7 = atomicAdd(&cursor[db.w], 1);
        bucket[p0] = make_int2(sa.x << 8, __float_as_int(wa.x));
        bucket[p1] = make_int2(sa.y << 8, __float_as_int(wa.y));
        bucket[p2] = make_int2(sa.z << 8, __float_as_int(wa.z));
        bucket[p3] = make_int2(sa.w << 8, __float_as_int(wa.w));
        bucket[p4] = make_int2(sb.x << 8, __float_as_int(wb.x));
        bucket[p5] = make_int2(sb.y << 8, __float_as_int(wb.y));
        bucket[p6] = make_int2(sb.z << 8, __float_as_int(wb.z));
        bucket[p7] = make_int2(sb.w << 8, __float_as_int(wb.w));
    } else {
        for (int i = i0; i < E; ++i) {
            int pos = atomicAdd(&cursor[ei[E + i]], 1);
            bucket[pos] = make_int2(ei[i] << 8, __float_as_int(ew[i]));
        }
    }
}

// ---------------- prep: blocks 0..3 convert W (bf16 hi/lo); blocks 4.. init cursor ----------------
__global__ __launch_bounds__(256) void k_prep(const float* __restrict__ Wl, const float* __restrict__ Wr,
                                              short* __restrict__ wt, int* __restrict__ cursor, int N) {
    int b = blockIdx.x;
    int t = threadIdx.x;
    if (b >= 4) {
        int i = (b - 4) * 256 + t;
        if (i < N) cursor[i] = i * MAXDEG;
        return;
    }
    int l = b >> 1, mat = b & 1;
    const float* W = (mat ? Wr : Wl) + (size_t)l * 16384;
    short* dst = wt + (size_t)b * 40960;
    int n = t >> 1, half = t & 1;   // n 0..127, half 0..1
    for (int chunk = 0; chunk < 4; ++chunk) {
        short hi16[16], lo16[16];
#pragma unroll
        for (int i = 0; i < 16; ++i) {
            int kk = half * 16 + i;
            float x = W[(size_t)(chunk * 32 + kk) * 128 + n];
            short h = bf16_rne(x);
            float r = x - bf16_to_f32(h);
            hi16[i] = h;
            lo16[i] = bf16_rne(r);
        }
        short* base = dst + chunk * 10240;
#pragma unroll
        for (int i = 0; i < 16; ++i) {
            base[n * 40 + half * 16 + i] = hi16[i];
            base[5120 + n * 40 + half * 16 + i] = lo16[i];
        }
    }
}

// ---------------- MFMA GEMM: O = H@W via split-bf16 (hi+lo), 64 rows/block, fp16 outputs ----------------
__global__ __launch_bounds__(256) void k_gemm_mfma(const float* __restrict__ H, const short* __restrict__ wt,
                                                   __half* __restrict__ Olh, __half* __restrict__ Orh, int N) {
    __shared__ __align__(16) short smem[2560 + 2560 + 10240];
    short* Ahi = smem;
    short* Alo = smem + 2560;
    short* Wst = smem + 5120;
    const short* wtm = wt + (size_t)blockIdx.y * 40960;
    __half* O = blockIdx.y ? Orh : Olh;
    int t = threadIdx.x;
    int w = t >> 6, lane = t & 63;
    int m = lane & 15, g = lane >> 4;
    int r0 = blockIdx.x * 64;
    f32x4 acc[8];
#pragma unroll
    for (int i = 0; i < 8; ++i) acc[i] = (f32x4){0.f, 0.f, 0.f, 0.f};

    int rr = t >> 2, q = t & 3;
    for (int chunk = 0; chunk < 4; ++chunk) {
        const short* wsrc = wtm + chunk * 10240;
#pragma unroll
        for (int i = 0; i < 5; ++i) {
            int u = t + i * 256;
            *(int4*)&Wst[u * 8] = *(const int4*)&wsrc[u * 8];
        }
        {
            int r = r0 + rr;
            float v[8];
            if (r < N) {
                float4 a = *(const float4*)&H[(size_t)r * 128 + chunk * 32 + q * 8];
                float4 b = *(const float4*)&H[(size_t)r * 128 + chunk * 32 + q * 8 + 4];
                v[0] = a.x; v[1] = a.y; v[2] = a.z; v[3] = a.w;
                v[4] = b.x; v[5] = b.y; v[6] = b.z; v[7] = b.w;
            } else {
#pragma unroll
                for (int i = 0; i < 8; ++i) v[i] = 0.f;
            }
            short hi8[8], lo8[8];
#pragma unroll
            for (int i = 0; i < 8; ++i) {
                short h = bf16_rne(v[i]);
                hi8[i] = h;
                lo8[i] = bf16_rne(v[i] - bf16_to_f32(h));
            }
            *(int4*)&Ahi[rr * 40 + q * 8] = *(int4*)hi8;
            *(int4*)&Alo[rr * 40 + q * 8] = *(int4*)lo8;
        }
        __syncthreads();
        bf16x8 ahi = *(bf16x8*)&Ahi[(w * 16 + m) * 40 + g * 8];
        bf16x8 alo = *(bf16x8*)&Alo[(w * 16 + m) * 40 + g * 8];
#pragma unroll
        for (int nf = 0; nf < 8; ++nf) {
            bf16x8 bhi = *(bf16x8*)&Wst[(nf * 16 + m) * 40 + g * 8];
            bf16x8 blo = *(bf16x8*)&Wst[5120 + (nf * 16 + m) * 40 + g * 8];
            acc[nf] = __builtin_amdgcn_mfma_f32_16x16x32_bf16(ahi, bhi, acc[nf], 0, 0, 0);
            acc[nf] = __builtin_amdgcn_mfma_f32_16x16x32_bf16(alo, bhi, acc[nf], 0, 0, 0);
            acc[nf] = __builtin_amdgcn_mfma_f32_16x16x32_bf16(ahi, blo, acc[nf], 0, 0, 0);
        }
        __syncthreads();
    }
#pragma unroll
    for (int nf = 0; nf < 8; ++nf)
#pragma unroll
        for (int j = 0; j < 4; ++j) {
            int row = r0 + w * 16 + g * 4 + j;
            if (row < N) O[(size_t)row * 128 + nf * 16 + m] = __float2half_rn(acc[nf][j]);
        }
}

// ---------------- Node kernel: persistent waves, grid-stride over nodes; ----------------
// ---------------- ping-pong pipelined 2-edge groups, fp16 xl+xr, packed score, DPP reduce ----------------

#define STAGE(IT, R0, R1, W0, W1, V0, V1)                                      \
    {                                                                          \
        int slot0 = (IT) * 8 + e4;                                             \
        int slot1 = slot0 + 4;                                                 \
        int s0i = __builtin_amdgcn_ds_bpermute(slot0 << 2, recAll.x);          \
        int w0i = __builtin_amdgcn_ds_bpermute(slot0 << 2, recAll.y);          \
        int s1i = __builtin_amdgcn_ds_bpermute(slot1 << 2, recAll.x);          \
        int w1i = __builtin_amdgcn_ds_bpermute(slot1 << 2, recAll.y);          \
        V0 = slot0 < deg; V1 = slot1 < deg;                                    \
        int off0 = (V0 ? s0i : nOff) + d02;                                    \
        int off1 = (V1 ? s1i : nOff) + d02;                                    \
        W0 = V0 ? __int_as_float(w0i) : 0.f;                                   \
        W1 = V1 ? __int_as_float(w1i) : 0.f;                                   \
        R0 = *(const int4*)(xlb + off0);                                       \
        R1 = *(const int4*)(xlb + off1);                                       \
    }

#define CONSUME(R0, R1, W0, W1, V0, V1)                                        \
    {                                                                          \
        __half2* x0h = (__half2*)&(R0);                                        \
        __half2* x1h = (__half2*)&(R1);                                        \
        uint32_t* x0u = (uint32_t*)&(R0);                                      \
        uint32_t* x1u = (uint32_t*)&(R1);                                      \
        __half2 w0h = __half2half2(__float2half_rn(W0));                       \
        __half2 w1h = __half2half2(__float2half_rn(W1));                       \
        float p0 = 0.f, p1 = 0.f;                                              \
        _Pragma("unroll")                                                      \
        for (int i = 0; i < 4; ++i) {                                          \
            __half2 t0 = __hfma2(w0h, weh[i], __hadd2(x0h[i], xrv[i]));        \
            __half2 t1 = __hfma2(w1h, weh[i], __hadd2(x1h[i], xrv[i]));        \
            t0 = hmax2(t0, __hmul2(t0, sl2));                                  \
            t1 = hmax2(t1, __hmul2(t1, sl2));                                  \
            p0 = fdot2(t0, ath[i], p0);                                        \
            p1 = fdot2(t1, ath[i], p1);                                        \
        }                                                                      \
        p0 = red8(p0);                                                         \
        p1 = red8(p1);                                                         \
        float e0 = exp2f(p0);                                                  \
        float e1 = exp2f(p1);                                                  \
        e0 = V0 ? e0 : 0.f;                                                    \
        e1 = V1 ? e1 : 0.f;                                                    \
        den += e0 + e1;                                                        \
        wacc += W0 + W1;                                                       \
        _Pragma("unroll")                                                      \
        for (int i = 0; i < 4; ++i) {                                          \
            a[2*i]   = fma_mix_lo(e0, x0u[i], a[2*i]);                         \
            a[2*i+1] = fma_mix_hi(e0, x0u[i], a[2*i+1]);                       \
            a[2*i]   = fma_mix_lo(e1, x1u[i], a[2*i]);                         \
            a[2*i+1] = fma_mix_hi(e1, x1u[i], a[2*i+1]);                       \
        }                                                                      \
    }

__global__ __launch_bounds__(256) void k_node(const __half* __restrict__ xl, const __half* __restrict__ xr_h,
                                              const int* __restrict__ cursor, const int2* __restrict__ bucket,
                                              const float* __restrict__ We, const float* __restrict__ att,
                                              const float* __restrict__ bias, float* __restrict__ out, int N) {
    int wid = threadIdx.x >> 6;
    int lane = threadIdx.x & 63;
    int sub = lane & 15, e4 = lane >> 4;
    int d0 = sub * 8;
    int d02 = d0 * 2;                     // byte offset within fp16 row
    const char* xlb = (const char*)xl;
    const float LOG2E = 1.44269504f;
    // node-independent setup (amortized over all nodes this wave handles)
    __half2 weh[4], ath[4];
    {
        float4 weA = *(const float4*)(We + d0),  weB = *(const float4*)(We + d0 + 4);
        float4 atA = *(const float4*)(att + d0), atB = *(const float4*)(att + d0 + 4);
        weh[0] = __floats2half2_rn(weA.x, weA.y); weh[1] = __floats2half2_rn(weA.z, weA.w);
        weh[2] = __floats2half2_rn(weB.x, weB.y); weh[3] = __floats2half2_rn(weB.z, weB.w);
        ath[0] = __floats2half2_rn(atA.x * LOG2E, atA.y * LOG2E);
        ath[1] = __floats2half2_rn(atA.z * LOG2E, atA.w * LOG2E);
        ath[2] = __floats2half2_rn(atB.x * LOG2E, atB.y * LOG2E);
        ath[3] = __floats2half2_rn(atB.z * LOG2E, atB.w * LOG2E);
    }
    __half2 sl2 = __half2half2(__float2half_rn(NEG_SLOPE));
    float4 biA = *(const float4*)(bias + d0), biB = *(const float4*)(bias + d0 + 4);
    int wave0 = blockIdx.x * 4 + wid;
    int stride = gridDim.x * 4;

    for (int n = wave0; n < N; n += stride) {
        int nOff = n << 8;                // byte offset of node's fp16 row
        __half2 xrv[4];
        {
            int4 xrr = *(const int4*)((const char*)xr_h + nOff + d02);
            __half2* xp = (__half2*)&xrr;
            xrv[0] = xp[0]; xrv[1] = xp[1]; xrv[2] = xp[2]; xrv[3] = xp[3];
        }
        int beg = n * MAXDEG;
        int deg = cursor[n] - beg;
        int iters = (deg + 7) >> 3;       // 8 edge slots per iteration
        int2 recAll = bucket[beg + lane]; // whole bucket row, one coalesced load
        float den = 0.f, wacc = 0.f;
        float a[8] = {};

        int4 pR0, pR1; float pW0, pW1; bool pV0, pV1;
        int4 qR0, qR1; float qW0, qW1; bool qV0, qV1;
        STAGE(0, pR0, pR1, pW0, pW1, pV0, pV1);
        for (int it = 0; it < iters; ) {  // wave-uniform trip count
            if (it + 1 < iters) STAGE(it + 1, qR0, qR1, qW0, qW1, qV0, qV1);
            CONSUME(pR0, pR1, pW0, pW1, pV0, pV1);
            ++it;
            if (it >= iters) break;
            if (it + 1 < iters) STAGE(it + 1, pR0, pR1, pW0, pW1, pV0, pV1);
            CONSUME(qR0, qR1, qW0, qW1, qV0, qV1);
            ++it;
        }
#pragma unroll
        for (int off = 16; off <= 32; off <<= 1) {
            den += __shfl_xor(den, off);
            wacc += __shfl_xor(wacc, off);
#pragma unroll
            for (int i = 0; i < 8; ++i) a[i] += __shfl_xor(a[i], off);
        }
        // self-loop: weight = mean incoming edge weight, source feature = xl[n]
        {
            float lw = wacc / (float)max(deg, 1);
            int4 rawn = *(const int4*)(xlb + nOff + d02);
            __half2* xh = (__half2*)&rawn;
            uint32_t* xu = (uint32_t*)&rawn;
            __half2 lwh = __half2half2(__float2half_rn(lw));
            float p = 0.f;
#pragma unroll
            for (int i = 0; i < 4; ++i) {
                __half2 t = __hfma2(lwh, weh[i], __hadd2(xh[i], xrv[i]));
                t = hmax2(t, __hmul2(t, sl2));
                p = fdot2(t, ath[i], p);
            }
            p = red8(p);
            float e = exp2f(p);
            den += e;
#pragma unroll
            for (int i = 0; i < 4; ++i) {
                a[2*i]   = fma_mix_lo(e, xu[i], a[2*i]);
                a[2*i+1] = fma_mix_hi(e, xu[i], a[2*i+1]);
            }
        }
        float inv = 1.f / den;
        float o[8];
        o[0] = a[0] * inv + biA.x; o[1] = a[1] * inv + biA.y;
        o[2] = a[2] * inv + biA.z; o[3] = a[3] * inv + biA.w;
        o[4] = a[4] * inv + biB.x; o[5] = a[5] * inv + biB.y;
        o[6] = a[6] * inv + biB.z; o[7] = a[7] * inv + biB.w;
#pragma unroll
        for (int i = 0; i < 8; ++i)              // ELU via hardware exp2 (abs err ~1e-7)
            o[i] = o[i] > 0.f ? o[i] : exp2f(o[i] * LOG2E) - 1.f;
        if (e4 == 0) {
            float* op = out + n * 128 + d0;
            *(float4*)op       = make_float4(o[0], o[1], o[2], o[3]);
            *(float4*)(op + 4) = make_float4(o[4], o[5], o[6], o[7]);
        }
    }
}

// ---------------- launch ----------------

extern "C" void kernel_launch(void* const* d_in, const int* in_sizes, int n_in,
                              void* d_out, int out_size, void* d_ws, size_t ws_size,
                              hipStream_t stream) {
    const int*   ei   = (const int*)d_in[0];
    const float* ew   = (const float*)d_in[1];
    const float* emb  = (const float*)d_in[2];
    const float* Wl   = (const float*)d_in[3];
    const float* Wr   = (const float*)d_in[4];
    const float* We   = (const float*)d_in[5];
    const float* att  = (const float*)d_in[6];
    const float* bias = (const float*)d_in[7];
    int E = in_sizes[1];
    int N = in_sizes[2] / 128;

    char* p = (char*)d_ws;
    auto alloc = [&](size_t bytes) { char* r = p; p += (bytes + 255) & ~(size_t)255; return r; };
    __half* xl    = (__half*)alloc((size_t)N * 128 * 2);
    __half* xr    = (__half*)alloc((size_t)N * 128 * 2);
    int2*   bucket= (int2*)alloc(((size_t)N * MAXDEG + 64) * 8);
    int*    cursor= (int*)alloc((size_t)N * 4);
    short*  wtbuf = (short*)alloc((size_t)4 * 40960 * 2);
    if ((size_t)(p - (char*)d_ws) > ws_size) return;

    int ib = (N + 255) / 256;
    int fb = (E / 8 + 255) / 256;
    k_prep<<<4 + ib, 256, 0, stream>>>(Wl, Wr, wtbuf, cursor, N);
    k_fillb<<<fb, 256, 0, stream>>>(ei, ew, cursor, bucket, E);

    int gb = (N + 63) / 64;
    int nb = 1024;                        // persistent waves, grid-stride over nodes
    const float* h = emb;
    for (int l = 0; l < 2; ++l) {
        float* outl = (float*)d_out;      // layer0 result lives in d_out, re-read by layer1 gemm
        k_gemm_mfma<<<dim3(gb, 2), 256, 0, stream>>>(h, wtbuf + (size_t)l * 81920, xl, xr, N);
        k_node<<<nb, 256, 0, stream>>>(xl, xr, cursor, bucket,
                                       We + (size_t)l * 128, att + (size_t)l * 128,
                                       bias + (size_t)l * 128, outl, N);
        h = outl;
    }
}

// Round 21
// 196.741 us; speedup vs baseline: 1.0902x; 1.0902x over previous
//
#include <hip/hip_runtime.h>
#include <hip/hip_fp16.h>
#include <cstdint>

#define NEG_SLOPE 0.2f
#define MAXDEG 64

typedef __attribute__((ext_vector_type(8))) short bf16x8;
typedef __attribute__((ext_vector_type(4))) float f32x4;
typedef _Float16 h2_t __attribute__((ext_vector_type(2)));

__device__ inline short bf16_rne(float x) {
    uint32_t u = __float_as_uint(x);
    return (short)((u + 0x7FFF + ((u >> 16) & 1)) >> 16);
}
__device__ inline float bf16_to_f32(short s) {
    uint32_t u = ((uint32_t)(uint16_t)s) << 16;
    return __uint_as_float(u);
}
__device__ inline float fdot2(__half2 a, __half2 b, float c) {
    return __builtin_amdgcn_fdot2(*(h2_t*)&a, *(h2_t*)&b, c, false);
}
// ROCm 7.2 hip_fp16.h lacks __hmax2 -> packed max via v_pk_max_f16
__device__ inline __half2 hmax2(__half2 a, __half2 b) {
    uint32_t au = *(uint32_t*)&a, bu = *(uint32_t*)&b, du;
    asm("v_pk_max_f16 %0, %1, %2" : "=v"(du) : "v"(au), "v"(bu));
    return *(__half2*)&du;
}
// mixed-precision FMA: f32 = f32 * f16(lo/hi of u32) + f32 — fuses cvt+fma
__device__ inline float fma_mix_lo(float e, uint32_t xh, float c) {
    float d;
    asm("v_fma_mix_f32 %0, %1, %2, %3 op_sel_hi:[0,1,0]" : "=v"(d) : "v"(e), "v"(xh), "v"(c));
    return d;
}
__device__ inline float fma_mix_hi(float e, uint32_t xh, float c) {
    float d;
    asm("v_fma_mix_f32 %0, %1, %2, %3 op_sel:[0,1,0] op_sel_hi:[0,1,0]" : "=v"(d) : "v"(e), "v"(xh), "v"(c));
    return d;
}
// DPP all-reduce within 8-lane groups (VALU-speed, avoids LDS-pipe shfl latency).
template <int CTRL, int RMASK, int BMASK, bool BC>
__device__ inline float dpp_add(float v) {
    int t = __builtin_amdgcn_update_dpp(0, __float_as_int(v), CTRL, RMASK, BMASK, BC);
    return v + __int_as_float(t);
}
__device__ inline float red8(float p) {                        // sum over 8-lane head group
    p = dpp_add<0xB1, 0xF, 0xF, true>(p);   // quad_perm [1,0,3,2] : xor 1
    p = dpp_add<0x4E, 0xF, 0xF, true>(p);   // quad_perm [2,3,0,1] : xor 2
    int a = __builtin_amdgcn_update_dpp(0, __float_as_int(p), 0x114, 0xF, 0xA, false); // row_shr:4
    int b = __builtin_amdgcn_update_dpp(0, __float_as_int(p), 0x104, 0xF, 0x5, false); // row_shl:4
    return p + __int_as_float(a) + __int_as_float(b);
}

// ---------------- bucketed CSR build: 1 atomic per edge, 8 edges/thread ----------------
// bucket record = { src<<8 (byte offset of fp16 row), w (f32 bits) }

__global__ __launch_bounds__(256) void k_fillb(const int* __restrict__ ei, const float* __restrict__ ew,
                                               int* __restrict__ cursor, int2* __restrict__ bucket, int E) {
    int i0 = (blockIdx.x * 256 + threadIdx.x) * 8;
    if (i0 >= E) return;
    if (i0 + 7 < E) {
        int4 sa = *(const int4*)&ei[i0];
        int4 sb = *(const int4*)&ei[i0 + 4];
        int4 da = *(const int4*)&ei[E + i0];
        int4 db = *(const int4*)&ei[E + i0 + 4];
        float4 wa = *(const float4*)&ew[i0];
        float4 wb = *(const float4*)&ew[i0 + 4];
        int p0 = atomicAdd(&cursor[da.x], 1);
        int p1 = atomicAdd(&cursor[da.y], 1);
        int p2 = atomicAdd(&cursor[da.z], 1);
        int p3 = atomicAdd(&cursor[da.w], 1);
        int p4 = atomicAdd(&cursor[db.x], 1);
        int p5 = atomicAdd(&cursor[db.y], 1);
        int p6 = atomicAdd(&cursor[db.z], 1);
        int p7 = atomicAdd(&cursor[db.w], 1);
        bucket[p0] = make_int2(sa.x << 8, __float_as_int(wa.x));
        bucket[p1] = make_int2(sa.y << 8, __float_as_int(wa.y));
        bucket[p2] = make_int2(sa.z << 8, __float_as_int(wa.z));
        bucket[p3] = make_int2(sa.w << 8, __float_as_int(wa.w));
        bucket[p4] = make_int2(sb.x << 8, __float_as_int(wb.x));
        bucket[p5] = make_int2(sb.y << 8, __float_as_int(wb.y));
        bucket[p6] = make_int2(sb.z << 8, __float_as_int(wb.z));
        bucket[p7] = make_int2(sb.w << 8, __float_as_int(wb.w));
    } else {
        for (int i = i0; i < E; ++i) {
            int pos = atomicAdd(&cursor[ei[E + i]], 1);
            bucket[pos] = make_int2(ei[i] << 8, __float_as_int(ew[i]));
        }
    }
}

// ---------------- prep: blocks 0..3 convert W (bf16 hi/lo); blocks 4.. init cursor ----------------
__global__ __launch_bounds__(256) void k_prep(const float* __restrict__ Wl, const float* __restrict__ Wr,
                                              short* __restrict__ wt, int* __restrict__ cursor, int N) {
    int b = blockIdx.x;
    int t = threadIdx.x;
    if (b >= 4) {
        int i = (b - 4) * 256 + t;
        if (i < N) cursor[i] = i * MAXDEG;
        return;
    }
    int l = b >> 1, mat = b & 1;
    const float* W = (mat ? Wr : Wl) + (size_t)l * 16384;
    short* dst = wt + (size_t)b * 40960;
    int n = t >> 1, half = t & 1;   // n 0..127, half 0..1
    for (int chunk = 0; chunk < 4; ++chunk) {
        short hi16[16], lo16[16];
#pragma unroll
        for (int i = 0; i < 16; ++i) {
            int kk = half * 16 + i;
            float x = W[(size_t)(chunk * 32 + kk) * 128 + n];
            short h = bf16_rne(x);
            float r = x - bf16_to_f32(h);
            hi16[i] = h;
            lo16[i] = bf16_rne(r);
        }
        short* base = dst + chunk * 10240;
#pragma unroll
        for (int i = 0; i < 16; ++i) {
            base[n * 40 + half * 16 + i] = hi16[i];
            base[5120 + n * 40 + half * 16 + i] = lo16[i];
        }
    }
}

// ---------------- MFMA GEMM: O = H@W via split-bf16 (hi+lo), 64 rows/block, fp16 outputs ----------------
__global__ __launch_bounds__(256) void k_gemm_mfma(const float* __restrict__ H, const short* __restrict__ wt,
                                                   __half* __restrict__ Olh, __half* __restrict__ Orh, int N) {
    __shared__ __align__(16) short smem[2560 + 2560 + 10240];
    short* Ahi = smem;
    short* Alo = smem + 2560;
    short* Wst = smem + 5120;
    const short* wtm = wt + (size_t)blockIdx.y * 40960;
    __half* O = blockIdx.y ? Orh : Olh;
    int t = threadIdx.x;
    int w = t >> 6, lane = t & 63;
    int m = lane & 15, g = lane >> 4;
    int r0 = blockIdx.x * 64;
    f32x4 acc[8];
#pragma unroll
    for (int i = 0; i < 8; ++i) acc[i] = (f32x4){0.f, 0.f, 0.f, 0.f};

    int rr = t >> 2, q = t & 3;
    for (int chunk = 0; chunk < 4; ++chunk) {
        const short* wsrc = wtm + chunk * 10240;
#pragma unroll
        for (int i = 0; i < 5; ++i) {
            int u = t + i * 256;
            *(int4*)&Wst[u * 8] = *(const int4*)&wsrc[u * 8];
        }
        {
            int r = r0 + rr;
            float v[8];
            if (r < N) {
                float4 a = *(const float4*)&H[(size_t)r * 128 + chunk * 32 + q * 8];
                float4 b = *(const float4*)&H[(size_t)r * 128 + chunk * 32 + q * 8 + 4];
                v[0] = a.x; v[1] = a.y; v[2] = a.z; v[3] = a.w;
                v[4] = b.x; v[5] = b.y; v[6] = b.z; v[7] = b.w;
            } else {
#pragma unroll
                for (int i = 0; i < 8; ++i) v[i] = 0.f;
            }
            short hi8[8], lo8[8];
#pragma unroll
            for (int i = 0; i < 8; ++i) {
                short h = bf16_rne(v[i]);
                hi8[i] = h;
                lo8[i] = bf16_rne(v[i] - bf16_to_f32(h));
            }
            *(int4*)&Ahi[rr * 40 + q * 8] = *(int4*)hi8;
            *(int4*)&Alo[rr * 40 + q * 8] = *(int4*)lo8;
        }
        __syncthreads();
        bf16x8 ahi = *(bf16x8*)&Ahi[(w * 16 + m) * 40 + g * 8];
        bf16x8 alo = *(bf16x8*)&Alo[(w * 16 + m) * 40 + g * 8];
#pragma unroll
        for (int nf = 0; nf < 8; ++nf) {
            bf16x8 bhi = *(bf16x8*)&Wst[(nf * 16 + m) * 40 + g * 8];
            bf16x8 blo = *(bf16x8*)&Wst[5120 + (nf * 16 + m) * 40 + g * 8];
            acc[nf] = __builtin_amdgcn_mfma_f32_16x16x32_bf16(ahi, bhi, acc[nf], 0, 0, 0);
            acc[nf] = __builtin_amdgcn_mfma_f32_16x16x32_bf16(alo, bhi, acc[nf], 0, 0, 0);
            acc[nf] = __builtin_amdgcn_mfma_f32_16x16x32_bf16(ahi, blo, acc[nf], 0, 0, 0);
        }
        __syncthreads();
    }
#pragma unroll
    for (int nf = 0; nf < 8; ++nf)
#pragma unroll
        for (int j = 0; j < 4; ++j) {
            int row = r0 + w * 16 + g * 4 + j;
            if (row < N) O[(size_t)row * 128 + nf * 16 + m] = __float2half_rn(acc[nf][j]);
        }
}

// ---------------- Node kernel: ping-pong pipelined 2-edge groups (R19 structure), ----------------
// ---------------- fp16 xl+xr, byte-offset records, packed-fp16 score, DPP reduce, fma_mix ----------------

#define STAGE(IT, R0, R1, W0, W1, V0, V1)                                      \
    {                                                                          \
        int slot0 = (IT) * 8 + e4;                                             \
        int slot1 = slot0 + 4;                                                 \
        int s0i = __builtin_amdgcn_ds_bpermute(slot0 << 2, recAll.x);          \
        int w0i = __builtin_amdgcn_ds_bpermute(slot0 << 2, recAll.y);          \
        int s1i = __builtin_amdgcn_ds_bpermute(slot1 << 2, recAll.x);          \
        int w1i = __builtin_amdgcn_ds_bpermute(slot1 << 2, recAll.y);          \
        V0 = slot0 < deg; V1 = slot1 < deg;                                    \
        int off0 = (V0 ? s0i : nOff) + d02;                                    \
        int off1 = (V1 ? s1i : nOff) + d02;                                    \
        W0 = V0 ? __int_as_float(w0i) : 0.f;                                   \
        W1 = V1 ? __int_as_float(w1i) : 0.f;                                   \
        R0 = *(const int4*)(xlb + off0);                                       \
        R1 = *(const int4*)(xlb + off1);                                       \
    }

#define CONSUME(R0, R1, W0, W1, V0, V1)                                        \
    {                                                                          \
        __half2* x0h = (__half2*)&(R0);                                        \
        __half2* x1h = (__half2*)&(R1);                                        \
        uint32_t* x0u = (uint32_t*)&(R0);                                      \
        uint32_t* x1u = (uint32_t*)&(R1);                                      \
        __half2 w0h = __half2half2(__float2half_rn(W0));                       \
        __half2 w1h = __half2half2(__float2half_rn(W1));                       \
        float p0 = 0.f, p1 = 0.f;                                              \
        _Pragma("unroll")                                                      \
        for (int i = 0; i < 4; ++i) {                                          \
            __half2 t0 = __hfma2(w0h, weh[i], __hadd2(x0h[i], xrv[i]));        \
            __half2 t1 = __hfma2(w1h, weh[i], __hadd2(x1h[i], xrv[i]));        \
            t0 = hmax2(t0, __hmul2(t0, sl2));                                  \
            t1 = hmax2(t1, __hmul2(t1, sl2));                                  \
            p0 = fdot2(t0, ath[i], p0);                                        \
            p1 = fdot2(t1, ath[i], p1);                                        \
        }                                                                      \
        p0 = red8(p0);                                                         \
        p1 = red8(p1);                                                         \
        float e0 = exp2f(p0);                                                  \
        float e1 = exp2f(p1);                                                  \
        e0 = V0 ? e0 : 0.f;                                                    \
        e1 = V1 ? e1 : 0.f;                                                    \
        den += e0 + e1;                                                        \
        wacc += W0 + W1;                                                       \
        _Pragma("unroll")                                                      \
        for (int i = 0; i < 4; ++i) {                                          \
            a[2*i]   = fma_mix_lo(e0, x0u[i], a[2*i]);                         \
            a[2*i+1] = fma_mix_hi(e0, x0u[i], a[2*i+1]);                       \
            a[2*i]   = fma_mix_lo(e1, x1u[i], a[2*i]);                         \
            a[2*i+1] = fma_mix_hi(e1, x1u[i], a[2*i+1]);                       \
        }                                                                      \
    }

__global__ __launch_bounds__(256) void k_node(const __half* __restrict__ xl, const __half* __restrict__ xr_h,
                                              const int* __restrict__ cursor, const int2* __restrict__ bucket,
                                              const float* __restrict__ We, const float* __restrict__ att,
                                              const float* __restrict__ bias, float* __restrict__ out, int N) {
    int wid = threadIdx.x >> 6;
    int lane = threadIdx.x & 63;
    int n = blockIdx.x * 4 + wid;
    if (n >= N) return;
    int sub = lane & 15, e4 = lane >> 4;
    int d0 = sub * 8;
    int d02 = d0 * 2;                     // byte offset within fp16 row
    int nOff = n << 8;                    // byte offset of node's fp16 row
    const char* xlb = (const char*)xl;
    const float LOG2E = 1.44269504f;
    __half2 weh[4], ath[4], xrv[4];
    {
        float4 weA = *(const float4*)(We + d0),  weB = *(const float4*)(We + d0 + 4);
        float4 atA = *(const float4*)(att + d0), atB = *(const float4*)(att + d0 + 4);
        weh[0] = __floats2half2_rn(weA.x, weA.y); weh[1] = __floats2half2_rn(weA.z, weA.w);
        weh[2] = __floats2half2_rn(weB.x, weB.y); weh[3] = __floats2half2_rn(weB.z, weB.w);
        ath[0] = __floats2half2_rn(atA.x * LOG2E, atA.y * LOG2E);
        ath[1] = __floats2half2_rn(atA.z * LOG2E, atA.w * LOG2E);
        ath[2] = __floats2half2_rn(atB.x * LOG2E, atB.y * LOG2E);
        ath[3] = __floats2half2_rn(atB.z * LOG2E, atB.w * LOG2E);
        int4 xrr = *(const int4*)((const char*)xr_h + nOff + d02);
        __half2* xp = (__half2*)&xrr;
        xrv[0] = xp[0]; xrv[1] = xp[1]; xrv[2] = xp[2]; xrv[3] = xp[3];
    }
    __half2 sl2 = __half2half2(__float2half_rn(NEG_SLOPE));
    int beg = n * MAXDEG;
    int deg = cursor[n] - beg;
    int iters = (deg + 7) >> 3;           // 8 edge slots per iteration
    int2 recAll = bucket[beg + lane];     // whole bucket row, one coalesced load
    float den = 0.f, wacc = 0.f;
    float a[8] = {};

    int4 pR0, pR1; float pW0, pW1; bool pV0, pV1;
    int4 qR0, qR1; float qW0, qW1; bool qV0, qV1;
    STAGE(0, pR0, pR1, pW0, pW1, pV0, pV1);
    for (int it = 0; it < iters; ) {      // all branches wave-uniform (same n)
        if (it + 1 < iters) STAGE(it + 1, qR0, qR1, qW0, qW1, qV0, qV1);
        CONSUME(pR0, pR1, pW0, pW1, pV0, pV1);
        ++it;
        if (it >= iters) break;
        if (it + 1 < iters) STAGE(it + 1, pR0, pR1, pW0, pW1, pV0, pV1);
        CONSUME(qR0, qR1, qW0, qW1, qV0, qV1);
        ++it;
    }
#pragma unroll
    for (int off = 16; off <= 32; off <<= 1) {
        den += __shfl_xor(den, off);
        wacc += __shfl_xor(wacc, off);
#pragma unroll
        for (int i = 0; i < 8; ++i) a[i] += __shfl_xor(a[i], off);
    }
    // self-loop: weight = mean incoming edge weight, source feature = xl[n] (same packed path)
    {
        float lw = wacc / (float)max(deg, 1);
        int4 rawn = *(const int4*)(xlb + nOff + d02);
        __half2* xh = (__half2*)&rawn;
        uint32_t* xu = (uint32_t*)&rawn;
        __half2 lwh = __half2half2(__float2half_rn(lw));
        float p = 0.f;
#pragma unroll
        for (int i = 0; i < 4; ++i) {
            __half2 t = __hfma2(lwh, weh[i], __hadd2(xh[i], xrv[i]));
            t = hmax2(t, __hmul2(t, sl2));
            p = fdot2(t, ath[i], p);
        }
        p = red8(p);
        float e = exp2f(p);
        den += e;
#pragma unroll
        for (int i = 0; i < 4; ++i) {
            a[2*i]   = fma_mix_lo(e, xu[i], a[2*i]);
            a[2*i+1] = fma_mix_hi(e, xu[i], a[2*i+1]);
        }
    }
    float inv = 1.f / den;
    float4 biA = *(const float4*)(bias + d0), biB = *(const float4*)(bias + d0 + 4);
    float o[8];
    o[0] = a[0] * inv + biA.x; o[1] = a[1] * inv + biA.y;
    o[2] = a[2] * inv + biA.z; o[3] = a[3] * inv + biA.w;
    o[4] = a[4] * inv + biB.x; o[5] = a[5] * inv + biB.y;
    o[6] = a[6] * inv + biB.z; o[7] = a[7] * inv + biB.w;
#pragma unroll
    for (int i = 0; i < 8; ++i)                  // ELU via hardware exp2 (abs err ~1e-7)
        o[i] = o[i] > 0.f ? o[i] : exp2f(o[i] * LOG2E) - 1.f;
    if (e4 == 0) {
        float* op = out + n * 128 + d0;
        *(float4*)op       = make_float4(o[0], o[1], o[2], o[3]);
        *(float4*)(op + 4) = make_float4(o[4], o[5], o[6], o[7]);
    }
}

// ---------------- launch ----------------

extern "C" void kernel_launch(void* const* d_in, const int* in_sizes, int n_in,
                              void* d_out, int out_size, void* d_ws, size_t ws_size,
                              hipStream_t stream) {
    const int*   ei   = (const int*)d_in[0];
    const float* ew   = (const float*)d_in[1];
    const float* emb  = (const float*)d_in[2];
    const float* Wl   = (const float*)d_in[3];
    const float* Wr   = (const float*)d_in[4];
    const float* We   = (const float*)d_in[5];
    const float* att  = (const float*)d_in[6];
    const float* bias = (const float*)d_in[7];
    int E = in_sizes[1];
    int N = in_sizes[2] / 128;

    char* p = (char*)d_ws;
    auto alloc = [&](size_t bytes) { char* r = p; p += (bytes + 255) & ~(size_t)255; return r; };
    __half* xl    = (__half*)alloc((size_t)N * 128 * 2);
    __half* xr    = (__half*)alloc((size_t)N * 128 * 2);
    int2*   bucket= (int2*)alloc(((size_t)N * MAXDEG + 64) * 8);
    int*    cursor= (int*)alloc((size_t)N * 4);
    short*  wtbuf = (short*)alloc((size_t)4 * 40960 * 2);
    if ((size_t)(p - (char*)d_ws) > ws_size) return;

    int ib = (N + 255) / 256;
    int fb = (E / 8 + 255) / 256;
    k_prep<<<4 + ib, 256, 0, stream>>>(Wl, Wr, wtbuf, cursor, N);
    k_fillb<<<fb, 256, 0, stream>>>(ei, ew, cursor, bucket, E);

    int gb = (N + 63) / 64;
    int nb = (N + 3) / 4;
    const float* h = emb;
    for (int l = 0; l < 2; ++l) {
        float* outl = (float*)d_out;      // layer0 result lives in d_out, re-read by layer1 gemm
        k_gemm_mfma<<<dim3(gb, 2), 256, 0, stream>>>(h, wtbuf + (size_t)l * 81920, xl, xr, N);
        k_node<<<nb, 256, 0, stream>>>(xl, xr, cursor, bucket,
                                       We + (size_t)l * 128, att + (size_t)l * 128,
                                       bias + (size_t)l * 128, outl, N);
        h = outl;
    }
}